// Round 9
// baseline (1338.864 us; speedup 1.0000x reference)
//
#include <hip/hip_runtime.h>

#define Bdim 8
#define Tdim 2048
#define Cdim 1024
#define CHUNK 64
#define NCHUNK 32
#define BC (Bdim*Cdim)

typedef float floatx4 __attribute__((ext_vector_type(4)));
typedef _Float16 half8 __attribute__((ext_vector_type(8)));
typedef _Float16 half4v __attribute__((ext_vector_type(4)));
typedef _Float16 half2v __attribute__((ext_vector_type(2)));

__device__ __forceinline__ void load16(const void* g, void* l) {
    __builtin_amdgcn_global_load_lds(
        (const __attribute__((address_space(1))) void*)g,
        (__attribute__((address_space(3))) void*)l, 16, 0, 0);
}

// ---------------- Kernel 1: fused {embedding gather + time-mix} UNION {W fp32->f16} ----------
__global__ __launch_bounds__(256) void mix_wconv(const int* __restrict__ tokens,
                                                 const float* __restrict__ xx_init,
                                                 const float* __restrict__ emb,
                                                 const float* __restrict__ tmk,
                                                 const float* __restrict__ tmv,
                                                 const float* __restrict__ tmr,
                                                 const float* __restrict__ Wk,
                                                 const float* __restrict__ Wv,
                                                 const float* __restrict__ Wr,
                                                 _Float16* __restrict__ xk,
                                                 _Float16* __restrict__ xv,
                                                 _Float16* __restrict__ xr,
                                                 _Float16* __restrict__ Wh) {
    int blk = blockIdx.x;
    if (blk < Bdim * Tdim) {
        int row = blk;                 // b*T + t
        int b = row >> 11;
        int t = row & (Tdim - 1);
        const float* cur = emb + (size_t)tokens[row] * Cdim;
        const float* prv = (t == 0) ? (xx_init + (size_t)b * Cdim)
                                    : (emb + (size_t)tokens[row - 1] * Cdim);
        int c = threadIdx.x * 4;
        float4 cu = *reinterpret_cast<const float4*>(cur + c);
        float4 pv = *reinterpret_cast<const float4*>(prv + c);
        float4 mk = *reinterpret_cast<const float4*>(tmk + c);
        float4 mv = *reinterpret_cast<const float4*>(tmv + c);
        float4 mr = *reinterpret_cast<const float4*>(tmr + c);
        float cf[4] = {cu.x, cu.y, cu.z, cu.w};
        float pf[4] = {pv.x, pv.y, pv.z, pv.w};
        float mkf[4] = {mk.x, mk.y, mk.z, mk.w};
        float mvf[4] = {mv.x, mv.y, mv.z, mv.w};
        float mrf[4] = {mr.x, mr.y, mr.z, mr.w};
        half4v hk, hv, hr;
        #pragma unroll
        for (int j = 0; j < 4; j++) {
            hk[j] = (_Float16)(mkf[j] * cf[j] + (1.0f - mkf[j]) * pf[j]);
            hv[j] = (_Float16)(mvf[j] * cf[j] + (1.0f - mvf[j]) * pf[j]);
            hr[j] = (_Float16)(mrf[j] * cf[j] + (1.0f - mrf[j]) * pf[j]);
        }
        size_t o = (size_t)row * Cdim + c;
        *reinterpret_cast<half4v*>(xk + o) = hk;
        *reinterpret_cast<half4v*>(xv + o) = hv;
        *reinterpret_cast<half4v*>(xr + o) = hr;
    } else {
        int idx2 = blk - Bdim * Tdim;      // 0..3071
        int which = idx2 >> 10;            // 0..2 (1024 blocks per W)
        const float* W = which == 0 ? Wk : (which == 1 ? Wv : Wr);
        _Float16* dst = Wh + (size_t)which * Cdim * Cdim;
        int i = ((idx2 & 1023) * 256 + threadIdx.x) * 4;
        float4 f = *reinterpret_cast<const float4*>(W + i);
        half4v h;
        h[0] = (_Float16)f.x; h[1] = (_Float16)f.y; h[2] = (_Float16)f.z; h[3] = (_Float16)f.w;
        *reinterpret_cast<half4v*>(dst + i) = h;
    }
}

// ---------------- Kernel 2: f16 GEMM (NT), 256x256 tile, BK=32, 2 blocks/CU ----------------
// out[m,n] = sum_c X[m,c] * W[n,c];  which=2 gets sigmoid.
// 2 LDS buffers (64 KB -> 2 blocks/CU, the occupancy lever): stage(kt+1) at top of
// iteration, 32 MFMA (~600+ cyc) cover the load latency, single vmcnt(0)+barrier
// per K-tile; co-resident block hides the residue (m114 mechanism).
// XOR swizzle swz(r)=(r>>1)&3 keeps ds_read_b128 conflict-free (rule #21).
__global__ __launch_bounds__(512, 4) void gemm_kvr(const _Float16* __restrict__ xk,
                                                   const _Float16* __restrict__ xv,
                                                   const _Float16* __restrict__ xr,
                                                   const _Float16* __restrict__ Wh,
                                                   _Float16* __restrict__ ko,
                                                   _Float16* __restrict__ vo,
                                                   _Float16* __restrict__ ro) {
    const int which = blockIdx.y;
    const _Float16* X = which == 0 ? xk : (which == 1 ? xv : xr);
    const _Float16* W = Wh + (size_t)which * Cdim * Cdim;
    _Float16* out     = which == 0 ? ko : (which == 1 ? vo : ro);

    // XCD-aware swizzle: all 4 n-tiles of one m-tile group on the same XCD
    const int lin = blockIdx.x;        // 0..255
    const int xcd = lin & 7;
    const int loc = lin >> 3;          // 0..31
    const int mt = xcd * 8 + (loc >> 2);   // 0..63
    const int nt = loc & 3;                // 0..3
    const int m0 = mt * 256;
    const int n0 = nt * 256;

    // 2 K-tile buffers: 2 * (16KB A + 16KB B) = 64 KB -> 2 blocks/CU
    __shared__ _Float16 As[2 * 8192];
    __shared__ _Float16 Bs[2 * 8192];

    const int tid = threadIdx.x;
    const int lane = tid & 63;
    const int wave = tid >> 6;         // 0..7
    const int wm = (wave >> 2) * 128;  // 2 M-groups
    const int wn = (wave & 3) * 64;    // 4 N-groups
    const int lr = lane & 15;          // fragment row within 16
    const int lk = lane >> 4;          // fragment k-block 0..3
    const int sw = (lr >> 1) & 3;      // row-swizzle, invariant across mi/ni

    const _Float16* Asrc = X + (size_t)m0 * Cdim;
    const _Float16* Bsrc = W + (size_t)n0 * Cdim;

    floatx4 acc[8][4] = {};

    // stage K-tile kt into buffer kt&1 (4 global_load_lds per thread).
    // LDS dest linear (slot e); global source colblock pre-swizzled.
    auto stage = [&](int kt) {
        const int p = kt & 1;
        const int k0 = kt * 32;
        #pragma unroll
        for (int i = 0; i < 2; i++) {
            int e = i * 512 + tid;         // 16B slot index, 0..1023
            int r = e >> 2;                // tile row 0..255
            int cp = e & 3;                // physical colblock
            int cl = cp ^ ((r >> 1) & 3);  // logical (global) colblock
            load16(Asrc + (size_t)r * Cdim + k0 + cl * 8, (char*)(As + p * 8192) + e * 16);
        }
        #pragma unroll
        for (int i = 0; i < 2; i++) {
            int e = i * 512 + tid;
            int r = e >> 2;
            int cp = e & 3;
            int cl = cp ^ ((r >> 1) & 3);
            load16(Bsrc + (size_t)r * Cdim + k0 + cl * 8, (char*)(Bs + p * 8192) + e * 16);
        }
    };

    // ds_read fragments from buffer kt&1 and run 32 MFMAs
    auto compute = [&](int kt) {
        const int p = kt & 1;
        const _Float16* ap = As + p * 8192 + (wm + lr) * 32 + (lk ^ sw) * 8;
        const _Float16* bp = Bs + p * 8192 + (wn + lr) * 32 + (lk ^ sw) * 8;
        half8 af[8], bf[4];
        #pragma unroll
        for (int mi = 0; mi < 8; mi++)
            af[mi] = *reinterpret_cast<const half8*>(ap + mi * 512);
        #pragma unroll
        for (int ni = 0; ni < 4; ni++)
            bf[ni] = *reinterpret_cast<const half8*>(bp + ni * 512);
        asm volatile("s_waitcnt lgkmcnt(0)" ::: "memory");
        __builtin_amdgcn_sched_barrier(0);             // rule #18
        __builtin_amdgcn_s_setprio(1);
        #pragma unroll
        for (int mi = 0; mi < 8; mi++)
            #pragma unroll
            for (int ni = 0; ni < 4; ni++)
                acc[mi][ni] = __builtin_amdgcn_mfma_f32_16x16x32_f16(af[mi], bf[ni], acc[mi][ni], 0, 0, 0);
        __builtin_amdgcn_s_setprio(0);
        __builtin_amdgcn_sched_barrier(0);
    };

    // prologue: fill buffer 0
    stage(0);
    asm volatile("s_waitcnt vmcnt(0)" ::: "memory");
    __builtin_amdgcn_s_barrier();

    // main loop: NK = 1024/32 = 32 K-tiles
    for (int kt = 0; kt < 32; ++kt) {
        if (kt < 31) stage(kt + 1);    // into buf (kt+1)&1, fully consumed at kt-1
        compute(kt);
        asm volatile("s_waitcnt vmcnt(0)" ::: "memory");  // kt+1 landed (issued ~600 cyc ago)
        __builtin_amdgcn_s_barrier();                     // all waves done reading buf kt&1
    }

    // epilogue: C/D layout col = lane&15 (n), row = (lane>>4)*4 + reg (m)
    #pragma unroll
    for (int mi = 0; mi < 8; mi++) {
        #pragma unroll
        for (int ni = 0; ni < 4; ni++) {
            #pragma unroll
            for (int reg = 0; reg < 4; reg++) {
                int mm = m0 + wm + mi * 16 + (lane >> 4) * 4 + reg;
                int nn = n0 + wn + ni * 16 + (lane & 15);
                float v = acc[mi][ni][reg];
                if (which == 2) v = 1.0f / (1.0f + __expf(-v));
                out[(size_t)mm * Cdim + nn] = (_Float16)v;
            }
        }
    }
}

// ---------------- Kernel 3: chunk-local WKV totals, 2 channels/thread ----------------
__global__ __launch_bounds__(256) void scan_pass1(const _Float16* __restrict__ kb,
                                                  const _Float16* __restrict__ vb,
                                                  const float* __restrict__ tdecay,
                                                  float* __restrict__ tot_a,
                                                  float* __restrict__ tot_b,
                                                  float* __restrict__ tot_p) {
    const int idx = blockIdx.x * 256 + threadIdx.x;   // 0 .. NCHUNK*BC/2-1
    const int j  = idx >> 12;                          // chunk 0..31
    const int pc = idx & 4095;                         // channel-pair
    const int bc = pc * 2;
    const int b  = bc >> 10;
    const int c  = bc & (Cdim - 1);
    const float w0 = -__expf(tdecay[c]);
    const float w1 = -__expf(tdecay[c + 1]);
    const size_t base = ((size_t)(b * Tdim + j * CHUNK)) * Cdim + c;
    float aa0 = 0.0f, bb0 = 0.0f, pp0 = -1e30f;
    float aa1 = 0.0f, bb1 = 0.0f, pp1 = -1e30f;
    const _Float16* kp = kb + base;
    const _Float16* vp = vb + base;
    #pragma unroll 4
    for (int t = 0; t < CHUNK; t++) {
        half2v k2 = *reinterpret_cast<const half2v*>(kp + (size_t)t * Cdim);
        half2v v2 = *reinterpret_cast<const half2v*>(vp + (size_t)t * Cdim);
        {
            float kt = (float)k2[0], vt = (float)v2[0];
            float ww2 = pp0 + w0;
            float p2 = fmaxf(ww2, kt);
            float e1 = __expf(ww2 - p2);
            float e2 = __expf(kt - p2);
            aa0 = e1 * aa0 + e2 * vt; bb0 = e1 * bb0 + e2; pp0 = p2;
        }
        {
            float kt = (float)k2[1], vt = (float)v2[1];
            float ww2 = pp1 + w1;
            float p2 = fmaxf(ww2, kt);
            float e1 = __expf(ww2 - p2);
            float e2 = __expf(kt - p2);
            aa1 = e1 * aa1 + e2 * vt; bb1 = e1 * bb1 + e2; pp1 = p2;
        }
    }
    int o = j * BC + bc;
    *reinterpret_cast<float2*>(tot_a + o) = make_float2(aa0, aa1);
    *reinterpret_cast<float2*>(tot_b + o) = make_float2(bb0, bb1);
    *reinterpret_cast<float2*>(tot_p + o) = make_float2(pp0, pp1);
}

// ---------------- Kernel 4: replay with inline combine prefix, 2 channels/thread ----------
__global__ __launch_bounds__(256) void scan_pass2c(const _Float16* __restrict__ kb,
                                                   const _Float16* __restrict__ vb,
                                                   const _Float16* __restrict__ rb,
                                                   const float* __restrict__ tdecay,
                                                   const float* __restrict__ tfirst,
                                                   const float* __restrict__ aa_init,
                                                   const float* __restrict__ bb_init,
                                                   const float* __restrict__ pp_init,
                                                   const float* __restrict__ tot_a,
                                                   const float* __restrict__ tot_b,
                                                   const float* __restrict__ tot_p,
                                                   float* __restrict__ partial,
                                                   float* __restrict__ ylast) {
    const int idx = blockIdx.x * 256 + threadIdx.x;
    const int j  = idx >> 12;                          // chunk 0..31 (block-uniform)
    const int pc = idx & 4095;
    const int bc = pc * 2;
    const int b  = bc >> 10;
    const int c  = bc & (Cdim - 1);
    const float w0 = -__expf(tdecay[c]);
    const float w1 = -__expf(tdecay[c + 1]);
    const float wL0 = w0 * (float)CHUNK;
    const float wL1 = w1 * (float)CHUNK;
    const float u0 = tfirst[c], u1 = tfirst[c + 1];

    float2 A = *reinterpret_cast<const float2*>(aa_init + bc);
    float2 Bv = *reinterpret_cast<const float2*>(bb_init + bc);
    float2 P = *reinterpret_cast<const float2*>(pp_init + bc);
    float aa0 = A.x, bb0 = Bv.x, pp0 = P.x;
    float aa1 = A.y, bb1 = Bv.y, pp1 = P.y;
    for (int jj = 0; jj < j; jj++) {
        int o = jj * BC + bc;
        float2 ta = *reinterpret_cast<const float2*>(tot_a + o);
        float2 tb = *reinterpret_cast<const float2*>(tot_b + o);
        float2 tp = *reinterpret_cast<const float2*>(tot_p + o);
        {
            float px = pp0 + wL0;
            float q = fmaxf(px, tp.x);
            float e1 = __expf(px - q), e2 = __expf(tp.x - q);
            aa0 = e1 * aa0 + e2 * ta.x; bb0 = e1 * bb0 + e2 * tb.x; pp0 = q;
        }
        {
            float px = pp1 + wL1;
            float q = fmaxf(px, tp.y);
            float e1 = __expf(px - q), e2 = __expf(tp.y - q);
            aa1 = e1 * aa1 + e2 * ta.y; bb1 = e1 * bb1 + e2 * tb.y; pp1 = q;
        }
    }

    const size_t base = ((size_t)(b * Tdim + j * CHUNK)) * Cdim + c;
    const _Float16* kp = kb + base;
    const _Float16* vp = vb + base;
    const _Float16* rp = rb + base;
    float sum0 = 0.0f, sum1 = 0.0f, ylv0 = 0.0f, ylv1 = 0.0f;
    #pragma unroll 4
    for (int t = 0; t < CHUNK; t++) {
        half2v k2 = *reinterpret_cast<const half2v*>(kp + (size_t)t * Cdim);
        half2v v2 = *reinterpret_cast<const half2v*>(vp + (size_t)t * Cdim);
        half2v r2 = *reinterpret_cast<const half2v*>(rp + (size_t)t * Cdim);
        {
            float kt = (float)k2[0], vt = (float)v2[0], rt = (float)r2[0];
            float ww = u0 + kt;
            float p = fmaxf(pp0, ww);
            float e1 = __expf(pp0 - p), e2 = __expf(ww - p);
            float wkv = (e1 * aa0 + e2 * vt) / (e1 * bb0 + e2);
            float y = rt * wkv;
            sum0 += y; ylv0 = y;
            float ww2 = pp0 + w0;
            float p2 = fmaxf(ww2, kt);
            float e1b = __expf(ww2 - p2), e2b = __expf(kt - p2);
            aa0 = e1b * aa0 + e2b * vt; bb0 = e1b * bb0 + e2b; pp0 = p2;
        }
        {
            float kt = (float)k2[1], vt = (float)v2[1], rt = (float)r2[1];
            float ww = u1 + kt;
            float p = fmaxf(pp1, ww);
            float e1 = __expf(pp1 - p), e2 = __expf(ww - p);
            float wkv = (e1 * aa1 + e2 * vt) / (e1 * bb1 + e2);
            float y = rt * wkv;
            sum1 += y; ylv1 = y;
            float ww2 = pp1 + w1;
            float p2 = fmaxf(ww2, kt);
            float e1b = __expf(ww2 - p2), e2b = __expf(kt - p2);
            aa1 = e1b * aa1 + e2b * vt; bb1 = e1b * bb1 + e2b; pp1 = p2;
        }
    }
    int o = j * BC + bc;
    *reinterpret_cast<float2*>(partial + o) = make_float2(sum0, sum1);
    if (j == NCHUNK - 1)
        *reinterpret_cast<float2*>(ylast + bc) = make_float2(ylv0, ylv1);
}

// ---------------- Kernel 6: z[b,c] = 0.5*(y_last + mean_t y), 2 ch/thread ----------------
__global__ __launch_bounds__(256) void reduce_z(const float* __restrict__ partial,
                                                const float* __restrict__ ylast,
                                                float* __restrict__ z) {
    int idx = blockIdx.x * 256 + threadIdx.x;   // 0..BC/2-1
    int bc = idx * 2;
    float s0 = 0.0f, s1 = 0.0f;
    #pragma unroll 4
    for (int jj = 0; jj < NCHUNK; jj++) {
        float2 pr = *reinterpret_cast<const float2*>(partial + jj * BC + bc);
        s0 += pr.x; s1 += pr.y;
    }
    float2 yl = *reinterpret_cast<const float2*>(ylast + bc);
    float2 zv;
    zv.x = 0.5f * (yl.x + s0 * (1.0f / (float)Tdim));
    zv.y = 0.5f * (yl.y + s1 * (1.0f / (float)Tdim));
    *reinterpret_cast<float2*>(z + bc) = zv;
}

// ---------------- Kernel 7: hx[b,d] = sum_c z[b,c]*Wo[d,c]; write twice ----------------
__global__ __launch_bounds__(256) void final_out(const float* __restrict__ z,
                                                 const float* __restrict__ Wo,
                                                 float* __restrict__ out) {
    int gw = (blockIdx.x * 256 + threadIdx.x) >> 6;   // global wave id, 0..BC-1
    int lane = threadIdx.x & 63;
    int b = gw >> 10;
    int d = gw & (Cdim - 1);
    const float* zr = z + (size_t)b * Cdim;
    const float* wr = Wo + (size_t)d * Cdim;
    float acc = 0.0f;
    #pragma unroll
    for (int i = lane; i < Cdim; i += 64) acc += zr[i] * wr[i];
    #pragma unroll
    for (int off = 32; off > 0; off >>= 1) acc += __shfl_down(acc, off);
    if (lane == 0) {
        out[(size_t)b * Cdim + d] = acc;
        out[(size_t)BC + (size_t)b * Cdim + d] = acc;
    }
}

extern "C" void kernel_launch(void* const* d_in, const int* in_sizes, int n_in,
                              void* d_out, int out_size, void* d_ws, size_t ws_size,
                              hipStream_t stream) {
    const int*   tokens  = (const int*)d_in[0];
    const float* xx_init = (const float*)d_in[1];
    const float* aa_init = (const float*)d_in[2];
    const float* bb_init = (const float*)d_in[3];
    const float* pp_init = (const float*)d_in[4];
    const float* emb     = (const float*)d_in[5];
    const float* tmk     = (const float*)d_in[6];
    const float* tmv     = (const float*)d_in[7];
    const float* tmr     = (const float*)d_in[8];
    const float* tdecay  = (const float*)d_in[9];
    const float* tfirst  = (const float*)d_in[10];
    const float* Wk      = (const float*)d_in[11];
    const float* Wv      = (const float*)d_in[12];
    const float* Wr      = (const float*)d_in[13];
    const float* Wo      = (const float*)d_in[14];
    float* out = (float*)d_out;

    char* ws = (char*)d_ws;
    size_t off = 0;
    auto alloc = [&](size_t bytes) -> void* {
        void* p = ws + off;
        off += (bytes + 255) & ~(size_t)255;
        return p;
    };
    _Float16* xkb = (_Float16*)alloc((size_t)Bdim * Tdim * Cdim * 2);
    _Float16* xvb = (_Float16*)alloc((size_t)Bdim * Tdim * Cdim * 2);
    _Float16* xrb = (_Float16*)alloc((size_t)Bdim * Tdim * Cdim * 2);
    _Float16* kb  = (_Float16*)alloc((size_t)Bdim * Tdim * Cdim * 2);
    _Float16* vb  = (_Float16*)alloc((size_t)Bdim * Tdim * Cdim * 2);
    _Float16* rb  = (_Float16*)alloc((size_t)Bdim * Tdim * Cdim * 2);
    _Float16* Wh = (_Float16*)alloc((size_t)3 * Cdim * Cdim * 2);
    float* tot_a = (float*)alloc((size_t)NCHUNK * BC * 4);
    float* tot_b = (float*)alloc((size_t)NCHUNK * BC * 4);
    float* tot_p = (float*)alloc((size_t)NCHUNK * BC * 4);
    float* partial = (float*)alloc((size_t)NCHUNK * BC * 4);
    float* ylast   = (float*)alloc((size_t)BC * 4);
    float* zbuf    = (float*)alloc((size_t)BC * 4);

    mix_wconv<<<Bdim * Tdim + 3072, 256, 0, stream>>>(tokens, xx_init, emb, tmk, tmv, tmr,
                                                      Wk, Wv, Wr, xkb, xvb, xrb, Wh);
    gemm_kvr<<<dim3(256, 3), 512, 0, stream>>>(xkb, xvb, xrb, Wh, kb, vb, rb);
    scan_pass1<<<(NCHUNK * BC / 2) / 256, 256, 0, stream>>>(kb, vb, tdecay, tot_a, tot_b, tot_p);
    scan_pass2c<<<(NCHUNK * BC / 2) / 256, 256, 0, stream>>>(kb, vb, rb, tdecay, tfirst,
                                                             aa_init, bb_init, pp_init,
                                                             tot_a, tot_b, tot_p, partial, ylast);
    reduce_z<<<(BC / 2) / 256, 256, 0, stream>>>(partial, ylast, zbuf);
    final_out<<<(BC / 4), 256, 0, stream>>>(zbuf, Wo, out);
}

// Round 10
// 412.887 us; speedup vs baseline: 3.2427x; 3.2427x over previous
//
#include <hip/hip_runtime.h>

#define Bdim 8
#define Tdim 2048
#define Cdim 1024
#define CHUNK 64
#define NCHUNK 32
#define BC (Bdim*Cdim)

typedef float floatx4 __attribute__((ext_vector_type(4)));
typedef _Float16 half8 __attribute__((ext_vector_type(8)));
typedef _Float16 half4v __attribute__((ext_vector_type(4)));
typedef _Float16 half2v __attribute__((ext_vector_type(2)));

__device__ __forceinline__ void load16(const void* g, void* l) {
    __builtin_amdgcn_global_load_lds(
        (const __attribute__((address_space(1))) void*)g,
        (__attribute__((address_space(3))) void*)l, 16, 0, 0);
}

// ---------------- Kernel 1: fused embedding gather + time-mix, fp32 -> f16 (x3) ----------------
__global__ __launch_bounds__(256) void fused_mix(const int* __restrict__ tokens,
                                                 const float* __restrict__ xx_init,
                                                 const float* __restrict__ emb,
                                                 const float* __restrict__ tmk,
                                                 const float* __restrict__ tmv,
                                                 const float* __restrict__ tmr,
                                                 _Float16* __restrict__ xk,
                                                 _Float16* __restrict__ xv,
                                                 _Float16* __restrict__ xr) {
    int row = blockIdx.x;              // b*T + t
    int b = row >> 11;
    int t = row & (Tdim - 1);
    const float* cur = emb + (size_t)tokens[row] * Cdim;
    const float* prv = (t == 0) ? (xx_init + (size_t)b * Cdim)
                                : (emb + (size_t)tokens[row - 1] * Cdim);
    int c = threadIdx.x * 4;
    float4 cu = *reinterpret_cast<const float4*>(cur + c);
    float4 pv = *reinterpret_cast<const float4*>(prv + c);
    float4 mk = *reinterpret_cast<const float4*>(tmk + c);
    float4 mv = *reinterpret_cast<const float4*>(tmv + c);
    float4 mr = *reinterpret_cast<const float4*>(tmr + c);
    float cf[4] = {cu.x, cu.y, cu.z, cu.w};
    float pf[4] = {pv.x, pv.y, pv.z, pv.w};
    float mkf[4] = {mk.x, mk.y, mk.z, mk.w};
    float mvf[4] = {mv.x, mv.y, mv.z, mv.w};
    float mrf[4] = {mr.x, mr.y, mr.z, mr.w};
    half4v hk, hv, hr;
    #pragma unroll
    for (int j = 0; j < 4; j++) {
        hk[j] = (_Float16)(mkf[j] * cf[j] + (1.0f - mkf[j]) * pf[j]);
        hv[j] = (_Float16)(mvf[j] * cf[j] + (1.0f - mvf[j]) * pf[j]);
        hr[j] = (_Float16)(mrf[j] * cf[j] + (1.0f - mrf[j]) * pf[j]);
    }
    size_t o = (size_t)row * Cdim + c;
    *reinterpret_cast<half4v*>(xk + o) = hk;
    *reinterpret_cast<half4v*>(xv + o) = hv;
    *reinterpret_cast<half4v*>(xr + o) = hr;
}

// ---------------- Kernel 1c: W fp32 -> f16 ----------------
__global__ __launch_bounds__(256) void wconv(const float* __restrict__ Wk,
                                             const float* __restrict__ Wv,
                                             const float* __restrict__ Wr,
                                             _Float16* __restrict__ Wh) {
    const float* W = blockIdx.y == 0 ? Wk : (blockIdx.y == 1 ? Wv : Wr);
    _Float16* dst = Wh + (size_t)blockIdx.y * Cdim * Cdim;
    int i = (blockIdx.x * 256 + threadIdx.x) * 4;
    float4 f = *reinterpret_cast<const float4*>(W + i);
    half4v h;
    h[0] = (_Float16)f.x; h[1] = (_Float16)f.y; h[2] = (_Float16)f.z; h[3] = (_Float16)f.w;
    *reinterpret_cast<half4v*>(dst + i) = h;
}

// ---------------- Kernel 2: deep-pipelined f16 GEMM (NT), 256x256 tile, BK=32 ----------------
// Best-measured configuration (142.7-146 us).  out[m,n] = sum_c X[m,c]*W[n,c]; which=2 sigmoid.
// 4 LDS buffers, stage 3 K-tiles ahead, counted s_waitcnt vmcnt(8), 2-phase K-tile,
// XOR swizzle swz(r)=(r>>1)&3 (conflict-free, rule #21).  NOTE: no min-waves in
// launch_bounds — r9 showed (512,4) forces VGPR=64 -> accumulator spills to scratch
// (4.2 GB scratch traffic, 7x regression).  Occupancy is register-bound, not LDS-bound.
__global__ __launch_bounds__(512, 2) void gemm_kvr(const _Float16* __restrict__ xk,
                                                   const _Float16* __restrict__ xv,
                                                   const _Float16* __restrict__ xr,
                                                   const _Float16* __restrict__ Wh,
                                                   _Float16* __restrict__ ko,
                                                   _Float16* __restrict__ vo,
                                                   _Float16* __restrict__ ro) {
    const int which = blockIdx.y;
    const _Float16* X = which == 0 ? xk : (which == 1 ? xv : xr);
    const _Float16* W = Wh + (size_t)which * Cdim * Cdim;
    _Float16* out     = which == 0 ? ko : (which == 1 ? vo : ro);

    const int lin = blockIdx.x;        // 0..255
    const int xcd = lin & 7;
    const int loc = lin >> 3;          // 0..31
    const int mt = xcd * 8 + (loc >> 2);   // 0..63
    const int nt = loc & 3;                // 0..3
    const int m0 = mt * 256;
    const int n0 = nt * 256;

    __shared__ _Float16 As[4 * 8192];
    __shared__ _Float16 Bs[4 * 8192];

    const int tid = threadIdx.x;
    const int lane = tid & 63;
    const int wave = tid >> 6;         // 0..7
    const int wm = (wave >> 2) * 128;  // 2 M-groups
    const int wn = (wave & 3) * 64;    // 4 N-groups
    const int lr = lane & 15;          // fragment row within 16
    const int lk = lane >> 4;          // fragment k-block 0..3
    const int sw = (lr >> 1) & 3;      // row-swizzle, invariant across mi/ni

    const _Float16* Asrc = X + (size_t)m0 * Cdim;
    const _Float16* Bsrc = W + (size_t)n0 * Cdim;

    floatx4 acc[8][4] = {};

    auto stageA = [&](int kt) {
        const int p = kt & 3;
        const int k0 = kt * 32;
        #pragma unroll
        for (int i = 0; i < 2; i++) {
            int e = i * 512 + tid;         // 16B slot index, 0..1023
            int r = e >> 2;                // tile row 0..255
            int cp = e & 3;                // physical colblock
            int cl = cp ^ ((r >> 1) & 3);  // logical (global) colblock
            load16(Asrc + (size_t)r * Cdim + k0 + cl * 8, (char*)(As + p * 8192) + e * 16);
        }
    };
    auto stageB = [&](int kt) {
        const int p = kt & 3;
        const int k0 = kt * 32;
        #pragma unroll
        for (int i = 0; i < 2; i++) {
            int e = i * 512 + tid;
            int r = e >> 2;
            int cp = e & 3;
            int cl = cp ^ ((r >> 1) & 3);
            load16(Bsrc + (size_t)r * Cdim + k0 + cl * 8, (char*)(Bs + p * 8192) + e * 16);
        }
    };

    auto ktile = [&](int kt, bool st) {
        const int p = kt & 3;
        const _Float16* ap = As + p * 8192 + (wm + lr) * 32 + (lk ^ sw) * 8;
        const _Float16* bp = Bs + p * 8192 + (wn + lr) * 32 + (lk ^ sw) * 8;
        half8 af[8], bf[4];
        #pragma unroll
        for (int mi = 0; mi < 4; mi++)
            af[mi] = *reinterpret_cast<const half8*>(ap + mi * 512);
        #pragma unroll
        for (int ni = 0; ni < 4; ni++)
            bf[ni] = *reinterpret_cast<const half8*>(bp + ni * 512);
        if (st) stageA(kt + 3);
        __builtin_amdgcn_s_barrier();
        asm volatile("s_waitcnt lgkmcnt(0)" ::: "memory");
        __builtin_amdgcn_sched_barrier(0);
        __builtin_amdgcn_s_setprio(1);
        #pragma unroll
        for (int mi = 0; mi < 4; mi++)
            #pragma unroll
            for (int ni = 0; ni < 4; ni++)
                acc[mi][ni] = __builtin_amdgcn_mfma_f32_16x16x32_f16(af[mi], bf[ni], acc[mi][ni], 0, 0, 0);
        __builtin_amdgcn_s_setprio(0);
        __builtin_amdgcn_sched_barrier(0);
        __builtin_amdgcn_s_barrier();
        #pragma unroll
        for (int mi = 4; mi < 8; mi++)
            af[mi] = *reinterpret_cast<const half8*>(ap + mi * 512);
        if (st) stageB(kt + 3);
        __builtin_amdgcn_s_barrier();
        asm volatile("s_waitcnt lgkmcnt(0)" ::: "memory");
        __builtin_amdgcn_sched_barrier(0);
        __builtin_amdgcn_s_setprio(1);
        #pragma unroll
        for (int mi = 4; mi < 8; mi++)
            #pragma unroll
            for (int ni = 0; ni < 4; ni++)
                acc[mi][ni] = __builtin_amdgcn_mfma_f32_16x16x32_f16(af[mi], bf[ni], acc[mi][ni], 0, 0, 0);
        __builtin_amdgcn_s_setprio(0);
        __builtin_amdgcn_sched_barrier(0);
    };

    stageA(0); stageB(0); stageA(1); stageB(1); stageA(2); stageB(2);
    asm volatile("s_waitcnt vmcnt(8)" ::: "memory");
    __builtin_amdgcn_s_barrier();

    for (int kt = 0; kt < 29; ++kt) {
        ktile(kt, true);
        asm volatile("s_waitcnt vmcnt(8)" ::: "memory");
        __builtin_amdgcn_s_barrier();
    }
    ktile(29, false);
    asm volatile("s_waitcnt vmcnt(4)" ::: "memory");
    __builtin_amdgcn_s_barrier();
    ktile(30, false);
    asm volatile("s_waitcnt vmcnt(0)" ::: "memory");
    __builtin_amdgcn_s_barrier();
    ktile(31, false);

    #pragma unroll
    for (int mi = 0; mi < 8; mi++) {
        #pragma unroll
        for (int ni = 0; ni < 4; ni++) {
            #pragma unroll
            for (int reg = 0; reg < 4; reg++) {
                int mm = m0 + wm + mi * 16 + (lane >> 4) * 4 + reg;
                int nn = n0 + wn + ni * 16 + (lane & 15);
                float v = acc[mi][ni][reg];
                if (which == 2) v = 1.0f / (1.0f + __expf(-v));
                out[(size_t)mm * Cdim + nn] = (_Float16)v;
            }
        }
    }
}

// ---------------- Kernel 3: chunk-local WKV totals (zero-start), CHUNK=64 ----------------
__global__ __launch_bounds__(256) void scan_pass1(const _Float16* __restrict__ kb,
                                                  const _Float16* __restrict__ vb,
                                                  const float* __restrict__ tdecay,
                                                  float* __restrict__ tot_a,
                                                  float* __restrict__ tot_b,
                                                  float* __restrict__ tot_p) {
    int idx = blockIdx.x * 256 + threadIdx.x;   // 0 .. NCHUNK*BC-1
    int j = idx >> 13;
    int bc = idx & (BC - 1);
    int b = bc >> 10;
    int c = bc & (Cdim - 1);
    float w = -__expf(tdecay[c]);
    float aa = 0.0f, bb = 0.0f, pp = -1e30f;
    const _Float16* kp = kb + ((size_t)(b * Tdim + j * CHUNK)) * Cdim + c;
    const _Float16* vp = vb + ((size_t)(b * Tdim + j * CHUNK)) * Cdim + c;
    #pragma unroll 4
    for (int t = 0; t < CHUNK; t++) {
        float kt = (float)kp[(size_t)t * Cdim];
        float vt = (float)vp[(size_t)t * Cdim];
        float ww2 = pp + w;
        float p2 = fmaxf(ww2, kt);
        float e1 = __expf(ww2 - p2);
        float e2 = __expf(kt - p2);
        aa = e1 * aa + e2 * vt;
        bb = e1 * bb + e2;
        pp = p2;
    }
    tot_a[idx] = aa; tot_b[idx] = bb; tot_p[idx] = pp;
}

// ---------------- Kernel 4: sequential combine of chunk totals ----------------
__global__ __launch_bounds__(256) void combine_chunks(const float* __restrict__ tot_a,
                                                      const float* __restrict__ tot_b,
                                                      const float* __restrict__ tot_p,
                                                      const float* __restrict__ aa_init,
                                                      const float* __restrict__ bb_init,
                                                      const float* __restrict__ pp_init,
                                                      const float* __restrict__ tdecay,
                                                      float* __restrict__ inc_a,
                                                      float* __restrict__ inc_b,
                                                      float* __restrict__ inc_p) {
    int idx = blockIdx.x * 256 + threadIdx.x;   // 0 .. BC-1
    int c = idx & (Cdim - 1);
    float w = -__expf(tdecay[c]);
    float wL = w * (float)CHUNK;
    float a = aa_init[idx], b = bb_init[idx], p = pp_init[idx];
    #pragma unroll 4
    for (int j = 0; j < NCHUNK; j++) {
        inc_a[j * BC + idx] = a;
        inc_b[j * BC + idx] = b;
        inc_p[j * BC + idx] = p;
        float ta = tot_a[j * BC + idx];
        float tb = tot_b[j * BC + idx];
        float tp = tot_p[j * BC + idx];
        float px = p + wL;
        float q = fmaxf(px, tp);
        float e1 = __expf(px - q);
        float e2 = __expf(tp - q);
        a = e1 * a + e2 * ta;
        b = e1 * b + e2 * tb;
        p = q;
    }
}

// ---------------- Kernel 5: replay with incoming state, CHUNK=64 ----------------
__global__ __launch_bounds__(256) void scan_pass2(const _Float16* __restrict__ kb,
                                                  const _Float16* __restrict__ vb,
                                                  const _Float16* __restrict__ rb,
                                                  const float* __restrict__ tdecay,
                                                  const float* __restrict__ tfirst,
                                                  const float* __restrict__ inc_a,
                                                  const float* __restrict__ inc_b,
                                                  const float* __restrict__ inc_p,
                                                  float* __restrict__ partial,
                                                  float* __restrict__ ylast) {
    int idx = blockIdx.x * 256 + threadIdx.x;
    int j = idx >> 13;
    int bc = idx & (BC - 1);
    int b = bc >> 10;
    int c = bc & (Cdim - 1);
    float w = -__expf(tdecay[c]);
    float u = tfirst[c];
    float aa = inc_a[idx], bb = inc_b[idx], pp = inc_p[idx];
    const size_t base = ((size_t)(b * Tdim + j * CHUNK)) * Cdim + c;
    const _Float16* kp = kb + base;
    const _Float16* vp = vb + base;
    const _Float16* rp = rb + base;
    float sum = 0.0f, ylv = 0.0f;
    #pragma unroll 4
    for (int t = 0; t < CHUNK; t++) {
        float kt = (float)kp[(size_t)t * Cdim];
        float vt = (float)vp[(size_t)t * Cdim];
        float rt = (float)rp[(size_t)t * Cdim];
        float ww = u + kt;
        float p = fmaxf(pp, ww);
        float e1 = __expf(pp - p);
        float e2 = __expf(ww - p);
        float wkv = (e1 * aa + e2 * vt) / (e1 * bb + e2);
        float y = rt * wkv;
        sum += y;
        ylv = y;
        float ww2 = pp + w;
        float p2 = fmaxf(ww2, kt);
        float e1b = __expf(ww2 - p2);
        float e2b = __expf(kt - p2);
        aa = e1b * aa + e2b * vt;
        bb = e1b * bb + e2b;
        pp = p2;
    }
    partial[idx] = sum;
    if (j == NCHUNK - 1) ylast[bc] = ylv;
}

// ---------------- Kernel 6: z[b,c] = 0.5*(y_last + mean_t y) ----------------
__global__ __launch_bounds__(256) void reduce_z(const float* __restrict__ partial,
                                                const float* __restrict__ ylast,
                                                float* __restrict__ z) {
    int idx = blockIdx.x * 256 + threadIdx.x;   // 0..BC-1
    float s = 0.0f;
    #pragma unroll 4
    for (int j = 0; j < NCHUNK; j++) s += partial[j * BC + idx];
    z[idx] = 0.5f * (ylast[idx] + s * (1.0f / (float)Tdim));
}

// ---------------- Kernel 7: hx[b,d] = sum_c z[b,c]*Wo[d,c]; write twice ----------------
__global__ __launch_bounds__(256) void final_out(const float* __restrict__ z,
                                                 const float* __restrict__ Wo,
                                                 float* __restrict__ out) {
    int gw = (blockIdx.x * 256 + threadIdx.x) >> 6;   // global wave id, 0..BC-1
    int lane = threadIdx.x & 63;
    int b = gw >> 10;
    int d = gw & (Cdim - 1);
    const float* zr = z + (size_t)b * Cdim;
    const float* wr = Wo + (size_t)d * Cdim;
    float acc = 0.0f;
    #pragma unroll
    for (int i = lane; i < Cdim; i += 64) acc += zr[i] * wr[i];
    #pragma unroll
    for (int off = 32; off > 0; off >>= 1) acc += __shfl_down(acc, off);
    if (lane == 0) {
        out[(size_t)b * Cdim + d] = acc;
        out[(size_t)BC + (size_t)b * Cdim + d] = acc;
    }
}

extern "C" void kernel_launch(void* const* d_in, const int* in_sizes, int n_in,
                              void* d_out, int out_size, void* d_ws, size_t ws_size,
                              hipStream_t stream) {
    const int*   tokens  = (const int*)d_in[0];
    const float* xx_init = (const float*)d_in[1];
    const float* aa_init = (const float*)d_in[2];
    const float* bb_init = (const float*)d_in[3];
    const float* pp_init = (const float*)d_in[4];
    const float* emb     = (const float*)d_in[5];
    const float* tmk     = (const float*)d_in[6];
    const float* tmv     = (const float*)d_in[7];
    const float* tmr     = (const float*)d_in[8];
    const float* tdecay  = (const float*)d_in[9];
    const float* tfirst  = (const float*)d_in[10];
    const float* Wk      = (const float*)d_in[11];
    const float* Wv      = (const float*)d_in[12];
    const float* Wr      = (const float*)d_in[13];
    const float* Wo      = (const float*)d_in[14];
    float* out = (float*)d_out;

    char* ws = (char*)d_ws;
    size_t off = 0;
    auto alloc = [&](size_t bytes) -> void* {
        void* p = ws + off;
        off += (bytes + 255) & ~(size_t)255;
        return p;
    };
    _Float16* xkb = (_Float16*)alloc((size_t)Bdim * Tdim * Cdim * 2);
    _Float16* xvb = (_Float16*)alloc((size_t)Bdim * Tdim * Cdim * 2);
    _Float16* xrb = (_Float16*)alloc((size_t)Bdim * Tdim * Cdim * 2);
    _Float16* kb  = (_Float16*)alloc((size_t)Bdim * Tdim * Cdim * 2);
    _Float16* vb  = (_Float16*)alloc((size_t)Bdim * Tdim * Cdim * 2);
    _Float16* rb  = (_Float16*)alloc((size_t)Bdim * Tdim * Cdim * 2);
    _Float16* Wh = (_Float16*)alloc((size_t)3 * Cdim * Cdim * 2);
    float* tot_a = (float*)alloc((size_t)NCHUNK * BC * 4);
    float* tot_b = (float*)alloc((size_t)NCHUNK * BC * 4);
    float* tot_p = (float*)alloc((size_t)NCHUNK * BC * 4);
    float* inc_a = (float*)alloc((size_t)NCHUNK * BC * 4);
    float* inc_b = (float*)alloc((size_t)NCHUNK * BC * 4);
    float* inc_p = (float*)alloc((size_t)NCHUNK * BC * 4);
    float* partial = (float*)alloc((size_t)NCHUNK * BC * 4);
    float* ylast   = (float*)alloc((size_t)BC * 4);
    float* zbuf    = (float*)alloc((size_t)BC * 4);

    fused_mix<<<Bdim * Tdim, 256, 0, stream>>>(tokens, xx_init, emb, tmk, tmv, tmr,
                                               xkb, xvb, xrb);
    wconv<<<dim3(1024, 3), 256, 0, stream>>>(Wk, Wv, Wr, Wh);
    gemm_kvr<<<dim3(256, 3), 512, 0, stream>>>(xkb, xvb, xrb, Wh, kb, vb, rb);
    scan_pass1<<<(NCHUNK * BC) / 256, 256, 0, stream>>>(kb, vb, tdecay, tot_a, tot_b, tot_p);
    combine_chunks<<<BC / 256, 256, 0, stream>>>(tot_a, tot_b, tot_p, aa_init, bb_init, pp_init,
                                                 tdecay, inc_a, inc_b, inc_p);
    scan_pass2<<<(NCHUNK * BC) / 256, 256, 0, stream>>>(kb, vb, rb, tdecay, tfirst,
                                                        inc_a, inc_b, inc_p, partial, ylast);
    reduce_z<<<BC / 256, 256, 0, stream>>>(partial, ylast, zbuf);
    final_out<<<(BC / 4), 256, 0, stream>>>(zbuf, Wo, out);
}